// Round 1
// baseline (438.038 us; speedup 1.0000x reference)
//
#include <hip/hip_runtime.h>

#define HDIM 128
#define NGRAPH 64
#define NCLASS 7

// ---------------- setup: degree, dinv, CSR build ----------------

__global__ void k_count(const int* __restrict__ col, int E, int* __restrict__ deg) {
  int e = blockIdx.x * blockDim.x + threadIdx.x;
  if (e < E) atomicAdd(&deg[col[e]], 1);
}

__global__ void k_dinv(const int* __restrict__ deg, float* __restrict__ dinv, int n) {
  int i = blockIdx.x * blockDim.x + threadIdx.x;
  if (i < n) dinv[i] = rsqrtf((float)(deg[i] + 1));  // +1 self-loop
}

// exclusive scan of deg -> off, tiles of 1024 (256 thr x 4)
__global__ void k_scan1(const int* __restrict__ in, int n, int* __restrict__ outLocal,
                        int* __restrict__ tileSums) {
  __shared__ int sh[256];
  int t = threadIdx.x;
  int base = blockIdx.x * 1024 + t * 4;
  int v[4], sum = 0;
#pragma unroll
  for (int j = 0; j < 4; j++) {
    int idx = base + j;
    int x = (idx < n) ? in[idx] : 0;
    v[j] = sum; sum += x;
  }
  sh[t] = sum; __syncthreads();
  for (int o = 1; o < 256; o <<= 1) {
    int val = (t >= o) ? sh[t - o] : 0;
    __syncthreads();
    sh[t] += val;
    __syncthreads();
  }
  int excl = (t == 0) ? 0 : sh[t - 1];
  if (t == 255) tileSums[blockIdx.x] = sh[255];
#pragma unroll
  for (int j = 0; j < 4; j++) {
    int idx = base + j;
    if (idx < n) outLocal[idx] = excl + v[j];
  }
}

__global__ void k_scan2(int* __restrict__ tileSums, int numTiles) {
  __shared__ int sh[128];
  int t = threadIdx.x;
  sh[t] = (t < numTiles) ? tileSums[t] : 0;
  __syncthreads();
  for (int o = 1; o < 128; o <<= 1) {
    int val = (t >= o) ? sh[t - o] : 0;
    __syncthreads();
    sh[t] += val;
    __syncthreads();
  }
  if (t < numTiles) tileSums[t] = (t == 0) ? 0 : sh[t - 1];
}

__global__ void k_scan3(int* __restrict__ off, const int* __restrict__ tileSums, int n, int E) {
  int i = blockIdx.x * blockDim.x + threadIdx.x;
  if (i < n) off[i] += tileSums[i >> 10];
  if (i == 0) off[n] = E;
}

__global__ void k_scatter(const int* __restrict__ row, const int* __restrict__ col, int E,
                          const int* __restrict__ off, int* __restrict__ cursor,
                          const float* __restrict__ dinv,
                          int* __restrict__ srcIdx, float* __restrict__ enorm) {
  int e = blockIdx.x * blockDim.x + threadIdx.x;
  if (e >= E) return;
  int r = row[e], c = col[e];
  int pos = off[c] + atomicAdd(&cursor[c], 1);
  srcIdx[pos] = r;
  enorm[pos] = dinv[r] * dinv[c];
}

// ---------------- layer 1 (scalar aggregation + outer product) ----------------

__global__ void k_layer1(const float* __restrict__ x, const int* __restrict__ off,
                         const int* __restrict__ srcIdx, const float* __restrict__ enorm,
                         const float* __restrict__ dinv, float* __restrict__ s, int n) {
  int i = blockIdx.x * blockDim.x + threadIdx.x;
  if (i >= n) return;
  float di = dinv[i];
  float acc = di * di * x[i];
  int e0 = off[i], e1 = off[i + 1];
  for (int e = e0; e < e1; e++) acc = fmaf(enorm[e], x[srcIdx[e]], acc);
  s[i] = acc;
}

__global__ void k_h1(const float* __restrict__ s, const float* __restrict__ W1,
                     const float* __restrict__ b1, float* __restrict__ h, int n) {
  int idx = blockIdx.x * blockDim.x + threadIdx.x;
  if (idx >= n * HDIM) return;
  int j = idx & (HDIM - 1);
  int i = idx >> 7;
  float v = fmaf(s[i], W1[j], b1[j]);
  h[idx] = fmaxf(v, 0.f);
}

// ---------------- fat aggregation: one wave per node, float2 per lane ----------------

__global__ void __launch_bounds__(64) k_agg(const float2* __restrict__ h,
                                            const int* __restrict__ off,
                                            const int* __restrict__ srcIdx,
                                            const float* __restrict__ enorm,
                                            const float* __restrict__ dinv,
                                            float2* __restrict__ out, int n) {
  int i = blockIdx.x;
  if (i >= n) return;
  int j = threadIdx.x;  // 64 lanes x float2 = 128 features
  float di = dinv[i];
  float nself = di * di;
  float2 self = h[(size_t)i * 64 + j];
  float2 acc = make_float2(nself * self.x, nself * self.y);
  int e0 = off[i], e1 = off[i + 1];
  for (int e = e0; e < e1; e++) {
    float w = enorm[e];
    float2 v = h[(size_t)srcIdx[e] * 64 + j];
    acc.x = fmaf(w, v.x, acc.x);
    acc.y = fmaf(w, v.y, acc.y);
  }
  out[(size_t)i * 64 + j] = acc;
}

// ---------------- GEMM: (n x 128) @ (128 x 128) + bias (+relu) ----------------
// 64-row x 64-col tile per block, 256 threads, 4x4 register tile.
// LDS: W slice [128][64] (32KB) + XOR-swizzled A tile [64][128] (32KB) = 64KB.

template <bool RELU>
__global__ void __launch_bounds__(256, 2)
k_gemm(const float* __restrict__ A, const float* __restrict__ W,
       const float* __restrict__ bias, float* __restrict__ out, int n) {
  __shared__ float Wl[128][64];
  __shared__ float As[64][128];  // As[r][k ^ r]
  const int t = threadIdx.x;
  const int colBase = blockIdx.y << 6;

  // stage W slice once
  for (int l = t; l < 128 * 16; l += 256) {
    int k = l >> 4, c4 = (l & 15) << 2;
    *(float4*)&Wl[k][c4] = *(const float4*)&W[k * 128 + colBase + c4];
  }

  const int cg = (t & 15) << 2;   // 4 cols
  const int rg = (t >> 4) << 2;   // 4 rows
  const float4 bv = *(const float4*)&bias[colBase + cg];
  const int numTiles = (n + 63) >> 6;

  for (int tile = blockIdx.x; tile < numTiles; tile += gridDim.x) {
    const int rowBase = tile << 6;
    __syncthreads();  // protect As from previous-iter readers
    for (int l = t; l < 2048; l += 256) {
      int r = l >> 5, k4 = (l & 31) << 2;
      int row = rowBase + r;
      float4 a = (row < n) ? *(const float4*)&A[(size_t)row * 128 + k4]
                           : make_float4(0.f, 0.f, 0.f, 0.f);
      As[r][(k4 + 0) ^ r] = a.x;
      As[r][(k4 + 1) ^ r] = a.y;
      As[r][(k4 + 2) ^ r] = a.z;
      As[r][(k4 + 3) ^ r] = a.w;
    }
    __syncthreads();

    float acc[4][4] = {};
#pragma unroll 4
    for (int k = 0; k < 128; k++) {
      float4 wv = *(const float4*)&Wl[k][cg];
      float a0 = As[rg + 0][k ^ (rg + 0)];
      float a1 = As[rg + 1][k ^ (rg + 1)];
      float a2 = As[rg + 2][k ^ (rg + 2)];
      float a3 = As[rg + 3][k ^ (rg + 3)];
      acc[0][0] = fmaf(a0, wv.x, acc[0][0]);
      acc[0][1] = fmaf(a0, wv.y, acc[0][1]);
      acc[0][2] = fmaf(a0, wv.z, acc[0][2]);
      acc[0][3] = fmaf(a0, wv.w, acc[0][3]);
      acc[1][0] = fmaf(a1, wv.x, acc[1][0]);
      acc[1][1] = fmaf(a1, wv.y, acc[1][1]);
      acc[1][2] = fmaf(a1, wv.z, acc[1][2]);
      acc[1][3] = fmaf(a1, wv.w, acc[1][3]);
      acc[2][0] = fmaf(a2, wv.x, acc[2][0]);
      acc[2][1] = fmaf(a2, wv.y, acc[2][1]);
      acc[2][2] = fmaf(a2, wv.z, acc[2][2]);
      acc[2][3] = fmaf(a2, wv.w, acc[2][3]);
      acc[3][0] = fmaf(a3, wv.x, acc[3][0]);
      acc[3][1] = fmaf(a3, wv.y, acc[3][1]);
      acc[3][2] = fmaf(a3, wv.z, acc[3][2]);
      acc[3][3] = fmaf(a3, wv.w, acc[3][3]);
    }

#pragma unroll
    for (int r = 0; r < 4; r++) {
      int row = rowBase + rg + r;
      if (row < n) {
        float4 o4;
        o4.x = acc[r][0] + bv.x;
        o4.y = acc[r][1] + bv.y;
        o4.z = acc[r][2] + bv.z;
        o4.w = acc[r][3] + bv.w;
        if (RELU) {
          o4.x = fmaxf(o4.x, 0.f); o4.y = fmaxf(o4.y, 0.f);
          o4.z = fmaxf(o4.z, 0.f); o4.w = fmaxf(o4.w, 0.f);
        }
        *(float4*)&out[(size_t)row * 128 + colBase + cg] = o4;
      }
    }
  }
}

// ---------------- pooling (batch is sorted) ----------------

__global__ void __launch_bounds__(128) k_pool(const float* __restrict__ h,
                                              const int* __restrict__ batch,
                                              float* __restrict__ pooled,
                                              float* __restrict__ gcount, int n) {
  int j = threadIdx.x;
  int start = blockIdx.x * 128;
  if (start >= n) return;
  int end = min(start + 128, n);
  float acc = 0.f;
  int cur = batch[start];
  int cnt = 0;
  for (int i = start; i < end; i++) {
    int g = batch[i];
    if (g != cur) {
      atomicAdd(&pooled[cur * HDIM + j], acc);
      if (j == 0) atomicAdd(&gcount[cur], (float)cnt);
      acc = 0.f; cnt = 0; cur = g;
    }
    acc += h[(size_t)i * HDIM + j];
    cnt++;
  }
  atomicAdd(&pooled[cur * HDIM + j], acc);
  if (j == 0) atomicAdd(&gcount[cur], (float)cnt);
}

// t1[g][j] = (pooledSum[g]/cnt[g]) . W3[:,j] + b3[j]   (layer-3 GEMM after pooling)
__global__ void k_mid(const float* __restrict__ pooled, const float* __restrict__ gcount,
                      const float* __restrict__ W3, const float* __restrict__ b3,
                      float* __restrict__ t1) {
  int g = blockIdx.x, j = threadIdx.x;
  float inv = 1.f / fmaxf(gcount[g], 1.f);
  float acc = 0.f;
  for (int k = 0; k < HDIM; k++) acc = fmaf(pooled[g * HDIM + k], W3[k * HDIM + j], acc);
  t1[g * HDIM + j] = acc * inv + b3[j];
}

__global__ void k_out(const float* __restrict__ t1, const float* __restrict__ Wl,
                      const float* __restrict__ bl, float* __restrict__ out) {
  int t = threadIdx.x;
  int g = t >> 3, c = t & 7;
  if (g >= NGRAPH || c >= NCLASS) return;
  float acc = 0.f;
  for (int k = 0; k < HDIM; k++) acc = fmaf(t1[g * HDIM + k], Wl[k * NCLASS + c], acc);
  out[g * NCLASS + c] = acc + bl[c];
}

// ---------------- host ----------------

extern "C" void kernel_launch(void* const* d_in, const int* in_sizes, int n_in,
                              void* d_out, int out_size, void* d_ws, size_t ws_size,
                              hipStream_t stream) {
  const float* x   = (const float*)d_in[0];
  const int*   ei  = (const int*)d_in[1];
  const int*   bat = (const int*)d_in[2];
  const float* W1  = (const float*)d_in[3];
  const float* b1  = (const float*)d_in[4];
  const float* W2  = (const float*)d_in[5];
  const float* b2  = (const float*)d_in[6];
  const float* W3  = (const float*)d_in[7];
  const float* b3  = (const float*)d_in[8];
  const float* Wl  = (const float*)d_in[9];
  const float* bl  = (const float*)d_in[10];
  float* out = (float*)d_out;

  const int n = in_sizes[0];       // N (F_IN == 1)
  const int E = in_sizes[1] / 2;
  const int* rowv = ei;            // edge_index[0] : message source
  const int* colv = ei + E;        // edge_index[1] : aggregation destination

  char* w = (char*)d_ws;
  size_t o = 0;
  auto alloc = [&](size_t bytes) {
    size_t r = (o + 255) & ~(size_t)255;
    o = r + bytes;
    return r;
  };
  // zero-init region (contiguous): deg, cursor, pooled, gcount
  size_t o_deg  = alloc((size_t)n * 4);
  size_t o_cur  = alloc((size_t)n * 4);
  size_t o_pool = alloc((size_t)NGRAPH * HDIM * 4);
  size_t o_gcnt = alloc((size_t)NGRAPH * 4);
  size_t zero_end = o;
  size_t o_off  = alloc(((size_t)n + 1) * 4);
  size_t o_ts   = alloc(256 * 4);
  size_t o_dinv = alloc((size_t)n * 4);
  size_t o_s    = alloc((size_t)n * 4);
  size_t o_t1   = alloc((size_t)NGRAPH * HDIM * 4);
  size_t o_src  = alloc((size_t)E * 4);
  size_t o_nrm  = alloc((size_t)E * 4);
  size_t o_bufA = alloc((size_t)n * HDIM * 4);
  size_t o_bufB = alloc((size_t)n * HDIM * 4);
  (void)ws_size; (void)n_in; (void)out_size;

  int*   deg    = (int*)(w + o_deg);
  int*   cursor = (int*)(w + o_cur);
  float* pooled = (float*)(w + o_pool);
  float* gcount = (float*)(w + o_gcnt);
  int*   off    = (int*)(w + o_off);
  int*   ts     = (int*)(w + o_ts);
  float* dinv   = (float*)(w + o_dinv);
  float* s      = (float*)(w + o_s);
  float* t1     = (float*)(w + o_t1);
  int*   srcIdx = (int*)(w + o_src);
  float* enorm  = (float*)(w + o_nrm);
  float* bufA   = (float*)(w + o_bufA);
  float* bufB   = (float*)(w + o_bufB);

  hipMemsetAsync(w + o_deg, 0, zero_end - o_deg, stream);

  int nTiles = (n + 1023) / 1024;
  k_count<<<(E + 255) / 256, 256, 0, stream>>>(colv, E, deg);
  k_dinv<<<(n + 255) / 256, 256, 0, stream>>>(deg, dinv, n);
  k_scan1<<<nTiles, 256, 0, stream>>>(deg, n, off, ts);
  k_scan2<<<1, 128, 0, stream>>>(ts, nTiles);
  k_scan3<<<(n + 255) / 256, 256, 0, stream>>>(off, ts, n, E);
  k_scatter<<<(E + 255) / 256, 256, 0, stream>>>(rowv, colv, E, off, cursor, dinv, srcIdx, enorm);

  // layer 1: scalar aggregation + outer product
  k_layer1<<<(n + 255) / 256, 256, 0, stream>>>(x, off, srcIdx, enorm, dinv, s, n);
  k_h1<<<(n * HDIM + 255) / 256, 256, 0, stream>>>(s, W1, b1, bufA, n);

  // layer 2: aggregate then GEMM(+bias+relu)
  k_agg<<<n, 64, 0, stream>>>((const float2*)bufA, off, srcIdx, enorm, dinv, (float2*)bufB, n);
  k_gemm<true><<<dim3(512, 2), 256, 0, stream>>>(bufB, W2, b2, bufA, n);

  // layer 3: aggregate, pool, then tiny GEMMs (pooling commutes with W3 since no relu)
  k_agg<<<n, 64, 0, stream>>>((const float2*)bufA, off, srcIdx, enorm, dinv, (float2*)bufB, n);
  k_pool<<<(n + 127) / 128, 128, 0, stream>>>(bufB, bat, pooled, gcount, n);
  k_mid<<<NGRAPH, HDIM, 0, stream>>>(pooled, gcount, W3, b3, t1);
  k_out<<<1, 512, 0, stream>>>(t1, Wl, bl, out);
}